// Round 3
// baseline (68.846 us; speedup 1.0000x reference)
//
#include <hip/hip_runtime.h>
#include <hip/hip_bf16.h>

namespace {

constexpr int T_DIM = 16384;   // number of tiles
constexpr int NT    = 16;      // tiles per block -> grid = 1024
constexpr int NBUF  = 4;       // LDS tile ring (= prefetch distance 2 + 2)

typedef __attribute__((ext_vector_type(8))) short bf16x8;
typedef __attribute__((ext_vector_type(4))) float f32x4;

__device__ inline short f2bf(float f) {
    union { __hip_bfloat16 h; short s; } u;
    u.h = __float2bfloat16(f);
    return u.s;
}

} // namespace

// 4 waves / 256 threads; wave w owns output rows [32w, 32w+32).
// T3+T4 pipeline: 4-buffer LDS ring, prefetch distance 2, counted
// s_waitcnt vmcnt(8) + raw s_barrier (never vmcnt(0) in the main loop).
// The ONLY loop VMEM ops are the stage DMAs -> vmcnt counting is exact.
// Swizzle (both-sides rule): LDS dest linear, global SOURCE chunk
// pre-swizzled g = c ^ ((c>>4)&7); reads apply the same XOR.
__global__ __launch_bounds__(256, 2) void fgbn_kernel(
    const float* __restrict__ x,
    const float* __restrict__ W1,
    const float* __restrict__ b1,
    const float* __restrict__ W2,
    const float* __restrict__ b2,
    float* __restrict__ out)
{
    __shared__ float tile[NBUF][4096];   // 4 x 16 KB W1 tiles
    __shared__ float b1s[NT * 64];       // 4 KB: b1 slice for this block
    __shared__ float w2s[NT * 64];       // 4 KB: W2 slice for this block

    const int tid  = threadIdx.x;
    const int lane = tid & 63;
    const int wave = tid >> 6;
    const int l15  = lane & 15;
    const int l4   = lane >> 4;
    const int t0   = blockIdx.x * NT;

    // ---- Prologue: plain VMEM first (all retired before loop waits) ----
    // A fragments from x: A[row=lane&15][k=8*(lane>>4)+e]; converted
    // immediately so the compiler's vmcnt waits land here, not in the loop.
    bf16x8 afrag[2][2];   // [rf][ks]
    #pragma unroll
    for (int rf = 0; rf < 2; ++rf) {
        const int row = wave * 32 + rf * 16 + l15;
        #pragma unroll
        for (int ks = 0; ks < 2; ++ks) {
            const float* src = x + row * 64 + ks * 32 + l4 * 8;
            f32x4 v0 = *reinterpret_cast<const f32x4*>(src);
            f32x4 v1 = *reinterpret_cast<const f32x4*>(src + 4);
            bf16x8 r;
            r[0] = f2bf(v0[0]); r[1] = f2bf(v0[1]); r[2] = f2bf(v0[2]); r[3] = f2bf(v0[3]);
            r[4] = f2bf(v1[0]); r[5] = f2bf(v1[1]); r[6] = f2bf(v1[2]); r[7] = f2bf(v1[3]);
            afrag[rf][ks] = r;
        }
    }
    // Each lane keeps b2[t0 + l15]; only the lane with l15==ti consumes it.
    const float b2lane = b2[t0 + l15];

    // ---- LDS DMA stages ----
    // b1 / W2 block slices: 1024 floats each, one 16B chunk per thread.
    __builtin_amdgcn_global_load_lds(
        (const __attribute__((address_space(1))) unsigned int*)(b1 + t0 * 64 + tid * 4),
        (__attribute__((address_space(3))) unsigned int*)&b1s[tid * 4], 16, 0, 0);
    __builtin_amdgcn_global_load_lds(
        (const __attribute__((address_space(1))) unsigned int*)(W2 + t0 * 64 + tid * 4),
        (__attribute__((address_space(3))) unsigned int*)&w2s[tid * 4], 16, 0, 0);

    // One 16 KB W1 tile -> tile[buf]; 4 chunks per thread (16B DMA each).
    auto stage = [&](int buf, int t) {
        const char* w1t = (const char*)W1 + (size_t)t * 16384;
        #pragma unroll
        for (int it = 0; it < 4; ++it) {
            const int c = wave * 256 + it * 64 + lane;   // linear LDS chunk
            const int g = c ^ ((c >> 4) & 7);            // pre-swizzled global chunk
            __builtin_amdgcn_global_load_lds(
                (const __attribute__((address_space(1))) unsigned int*)(w1t + (size_t)g * 16),
                (__attribute__((address_space(3))) unsigned int*)&tile[buf][c * 4],
                16, 0, 0);
        }
    };

    stage(0, t0);
    stage(1, t0 + 1);

    f32x4 outv[2] = {{0.f,0.f,0.f,0.f},{0.f,0.f,0.f,0.f}};   // [rf][r]

    for (int ti = 0; ti < NT; ++ti) {
        // 1. Issue stage for tile ti+2 (keeps 2 tiles in flight across barrier).
        //    WAR-safe: target buffer was last read at iter ti-2, and all waves
        //    passed barrier(ti-1) before we got here.
        if (ti + 2 < NT) stage((ti + 2) & (NBUF - 1), t0 + ti + 2);

        // 2. Counted wait: stage(ti) retired iff <= 4*(stages issued after it).
        if (ti < NT - 2)       asm volatile("s_waitcnt vmcnt(8)" ::: "memory");
        else if (ti == NT - 2) asm volatile("s_waitcnt vmcnt(4)" ::: "memory");
        else                   asm volatile("s_waitcnt vmcnt(0)" ::: "memory");
        // 3. Raw barrier: all waves' stage(ti) contributions have landed.
        __builtin_amdgcn_s_barrier();

        // 4. Compute tile ti from the ring.
        const float* lbuf = tile[ti & (NBUF - 1)];

        float b1v[4], w2v[4];
        #pragma unroll
        for (int nf = 0; nf < 4; ++nf) {
            b1v[nf] = b1s[ti * 64 + nf * 16 + l15];   // broadcast across l4 groups
            w2v[nf] = w2s[ti * 64 + nf * 16 + l15];
        }

        f32x4 acc[2][4];
        #pragma unroll
        for (int rf = 0; rf < 2; ++rf)
            #pragma unroll
            for (int nf = 0; nf < 4; ++nf)
                acc[rf][nf] = (f32x4){0.f, 0.f, 0.f, 0.f};

        #pragma unroll
        for (int nf = 0; nf < 4; ++nf) {
            const int j = nf * 16 + l15;
            const int sw = j & 7;
            bf16x8 bks[2];
            #pragma unroll
            for (int ks = 0; ks < 2; ++ks) {
                const int c0 = j * 16 + ks * 8 + l4 * 2;
                f32x4 v0 = *reinterpret_cast<const f32x4*>(&lbuf[(c0 ^ sw) * 4]);
                f32x4 v1 = *reinterpret_cast<const f32x4*>(&lbuf[((c0 + 1) ^ sw) * 4]);
                bf16x8 r;
                r[0] = f2bf(v0[0]); r[1] = f2bf(v0[1]); r[2] = f2bf(v0[2]); r[3] = f2bf(v0[3]);
                r[4] = f2bf(v1[0]); r[5] = f2bf(v1[1]); r[6] = f2bf(v1[2]); r[7] = f2bf(v1[3]);
                bks[ks] = r;
            }
            #pragma unroll
            for (int ks = 0; ks < 2; ++ks)
                #pragma unroll
                for (int rf = 0; rf < 2; ++rf)
                    acc[rf][nf] = __builtin_amdgcn_mfma_f32_16x16x32_bf16(
                        afrag[rf][ks], bks[ks], acc[rf][nf], 0, 0, 0);
        }

        // Stage 2: y[b,t] = 2*(sum_j relu(h+b1)*W2 + b2); butterfly over the
        // 16-lane group leaves the sum in all lanes; lane l15==ti keeps tile ti
        // (and adds ITS b2lane == b2[t0+ti]).
        #pragma unroll
        for (int rf = 0; rf < 2; ++rf) {
            #pragma unroll
            for (int r = 0; r < 4; ++r) {
                float s = 0.f;
                #pragma unroll
                for (int nf = 0; nf < 4; ++nf) {
                    float p = fmaxf(acc[rf][nf][r] + b1v[nf], 0.f);
                    s = fmaf(p, w2v[nf], s);
                }
                s += __shfl_xor(s, 1);
                s += __shfl_xor(s, 2);
                s += __shfl_xor(s, 4);
                s += __shfl_xor(s, 8);
                const float v = 2.f * (s + b2lane);
                outv[rf][r] = (l15 == ti) ? v : outv[rf][r];
            }
        }
    }

    // Coalesced epilogue: 16 lanes cover t0..t0+15 -> full 64B lines.
    #pragma unroll
    for (int rf = 0; rf < 2; ++rf)
        #pragma unroll
        for (int r = 0; r < 4; ++r) {
            const int brow = wave * 32 + rf * 16 + l4 * 4 + r;
            out[(size_t)brow * T_DIM + t0 + l15] = outv[rf][r];
        }
}

extern "C" void kernel_launch(void* const* d_in, const int* in_sizes, int n_in,
                              void* d_out, int out_size, void* d_ws, size_t ws_size,
                              hipStream_t stream) {
    const float* x  = (const float*)d_in[0];
    const float* W1 = (const float*)d_in[1];
    const float* b1 = (const float*)d_in[2];
    const float* W2 = (const float*)d_in[3];
    const float* b2 = (const float*)d_in[4];
    float* out = (float*)d_out;

    dim3 grid(T_DIM / NT);
    dim3 block(256);
    hipLaunchKernelGGL(fgbn_kernel, grid, block, 0, stream,
                       x, W1, b1, W2, b2, out);
}

// Round 4
// 63.804 us; speedup vs baseline: 1.0790x; 1.0790x over previous
//
#include <hip/hip_runtime.h>
#include <hip/hip_bf16.h>

namespace {

constexpr int T_DIM = 16384;   // number of tiles
constexpr int NT    = 16;      // tiles per block -> grid = 1024 (4 blocks/CU, all resident)

typedef __attribute__((ext_vector_type(8))) short bf16x8;
typedef __attribute__((ext_vector_type(4))) float f32x4;

__device__ inline short f2bf(float f) {
    union { __hip_bfloat16 h; short s; } u;
    u.h = __float2bfloat16(f);
    return u.s;
}

} // namespace

// 4 waves / 256 threads; wave w owns output rows [32w, 32w+32).
// Double-buffered LDS stage with COUNTED waits (T4): per iter ->
//   stage(ti+1); s_waitcnt vmcnt(4); s_barrier; compute(ti); s_barrier
// Never vmcnt(0) in the main loop: the newest burst stays in flight across
// both barriers. Only loop VMEM = stage DMA, so vmcnt counting is exact.
// 40 KB LDS keeps 4 blocks/CU (the R3 regression was the 72KB->2 blocks drop).
__global__ __launch_bounds__(256, 4) void fgbn_kernel(
    const float* __restrict__ x,
    const float* __restrict__ W1,
    const float* __restrict__ b1,
    const float* __restrict__ W2,
    const float* __restrict__ b2,
    float* __restrict__ out)
{
    __shared__ float tile[2][4096];      // 2 x 16 KB W1 tiles
    __shared__ float b1s[NT * 64];       // 4 KB: b1 slice for this block
    __shared__ float w2s[NT * 64];       // 4 KB: W2 slice for this block

    const int tid  = threadIdx.x;
    const int lane = tid & 63;
    const int wave = tid >> 6;
    const int l15  = lane & 15;
    const int l4   = lane >> 4;
    const int t0   = blockIdx.x * NT;

    // ---- Prologue: plain VMEM (retired before the loop's first wait) ----
    bf16x8 afrag[2][2];   // [rf][ks]  A[row=lane&15][k=8*(lane>>4)+e]
    #pragma unroll
    for (int rf = 0; rf < 2; ++rf) {
        const int row = wave * 32 + rf * 16 + l15;
        #pragma unroll
        for (int ks = 0; ks < 2; ++ks) {
            const float* src = x + row * 64 + ks * 32 + l4 * 8;
            f32x4 v0 = *reinterpret_cast<const f32x4*>(src);
            f32x4 v1 = *reinterpret_cast<const f32x4*>(src + 4);
            bf16x8 r;
            r[0] = f2bf(v0[0]); r[1] = f2bf(v0[1]); r[2] = f2bf(v0[2]); r[3] = f2bf(v0[3]);
            r[4] = f2bf(v1[0]); r[5] = f2bf(v1[1]); r[6] = f2bf(v1[2]); r[7] = f2bf(v1[3]);
            afrag[rf][ks] = r;
        }
    }
    // Each lane keeps b2[t0 + l15]; the surviving lane l15==ti consumes it.
    const float b2lane = b2[t0 + l15];

    // ---- LDS DMA stages (vmcnt-tracked, in-order retirement) ----
    __builtin_amdgcn_global_load_lds(
        (const __attribute__((address_space(1))) unsigned int*)(b1 + t0 * 64 + tid * 4),
        (__attribute__((address_space(3))) unsigned int*)&b1s[tid * 4], 16, 0, 0);
    __builtin_amdgcn_global_load_lds(
        (const __attribute__((address_space(1))) unsigned int*)(W2 + t0 * 64 + tid * 4),
        (__attribute__((address_space(3))) unsigned int*)&w2s[tid * 4], 16, 0, 0);

    // One 16 KB W1 tile -> tile[buf]; 4 x 16B DMA per thread.
    // Swizzle (both-sides rule): LDS dest linear, global SOURCE chunk
    // pre-swizzled g = c ^ ((c>>4)&7); fragment reads apply the same XOR.
    auto stage = [&](int buf, int t) {
        const char* w1t = (const char*)W1 + (size_t)t * 16384;
        #pragma unroll
        for (int it = 0; it < 4; ++it) {
            const int c = wave * 256 + it * 64 + lane;   // linear LDS chunk
            const int g = c ^ ((c >> 4) & 7);            // pre-swizzled global chunk
            __builtin_amdgcn_global_load_lds(
                (const __attribute__((address_space(1))) unsigned int*)(w1t + (size_t)g * 16),
                (__attribute__((address_space(3))) unsigned int*)&tile[buf][c * 4],
                16, 0, 0);
        }
    };

    stage(0, t0);

    f32x4 outv[2] = {{0.f,0.f,0.f,0.f},{0.f,0.f,0.f,0.f}};   // [rf][r]

    for (int ti = 0; ti < NT; ++ti) {
        // 1. Prefetch tile ti+1 into the other buffer (stays in flight
        //    across the barriers below).
        if (ti + 1 < NT) stage((ti + 1) & 1, t0 + ti + 1);

        // 2. Counted wait: own stage(ti) retired; stage(ti+1) (newest 4 loads)
        //    still outstanding. At ti=0 this also covers b1s/w2s (oldest).
        if (ti + 1 < NT) asm volatile("s_waitcnt vmcnt(4)" ::: "memory");
        else             asm volatile("s_waitcnt vmcnt(0)" ::: "memory");
        // 3. RAW barrier: every wave's stage(ti) contribution has landed.
        __builtin_amdgcn_s_barrier();

        // 4. Compute tile ti.
        const float* lbuf = tile[ti & 1];

        float b1v[4], w2v[4];
        #pragma unroll
        for (int nf = 0; nf < 4; ++nf) {
            b1v[nf] = b1s[ti * 64 + nf * 16 + l15];
            w2v[nf] = w2s[ti * 64 + nf * 16 + l15];
        }

        f32x4 acc[2][4];
        #pragma unroll
        for (int rf = 0; rf < 2; ++rf)
            #pragma unroll
            for (int nf = 0; nf < 4; ++nf)
                acc[rf][nf] = (f32x4){0.f, 0.f, 0.f, 0.f};

        #pragma unroll
        for (int nf = 0; nf < 4; ++nf) {
            const int j = nf * 16 + l15;
            const int sw = j & 7;
            bf16x8 bks[2];
            #pragma unroll
            for (int ks = 0; ks < 2; ++ks) {
                const int c0 = j * 16 + ks * 8 + l4 * 2;
                f32x4 v0 = *reinterpret_cast<const f32x4*>(&lbuf[(c0 ^ sw) * 4]);
                f32x4 v1 = *reinterpret_cast<const f32x4*>(&lbuf[((c0 + 1) ^ sw) * 4]);
                bf16x8 r;
                r[0] = f2bf(v0[0]); r[1] = f2bf(v0[1]); r[2] = f2bf(v0[2]); r[3] = f2bf(v0[3]);
                r[4] = f2bf(v1[0]); r[5] = f2bf(v1[1]); r[6] = f2bf(v1[2]); r[7] = f2bf(v1[3]);
                bks[ks] = r;
            }
            #pragma unroll
            for (int ks = 0; ks < 2; ++ks)
                #pragma unroll
                for (int rf = 0; rf < 2; ++rf)
                    acc[rf][nf] = __builtin_amdgcn_mfma_f32_16x16x32_bf16(
                        afrag[rf][ks], bks[ks], acc[rf][nf], 0, 0, 0);
        }

        // Stage 2: y[b,t] = 2*(sum_j relu(h+b1)*W2 + b2); 16-lane butterfly
        // leaves the sum in all lanes; lane l15==ti keeps tile ti.
        #pragma unroll
        for (int rf = 0; rf < 2; ++rf) {
            #pragma unroll
            for (int r = 0; r < 4; ++r) {
                float s = 0.f;
                #pragma unroll
                for (int nf = 0; nf < 4; ++nf) {
                    float p = fmaxf(acc[rf][nf][r] + b1v[nf], 0.f);
                    s = fmaf(p, w2v[nf], s);
                }
                s += __shfl_xor(s, 1);
                s += __shfl_xor(s, 2);
                s += __shfl_xor(s, 4);
                s += __shfl_xor(s, 8);
                const float v = 2.f * (s + b2lane);
                outv[rf][r] = (l15 == ti) ? v : outv[rf][r];
            }
        }

        // 5. WAR barrier: next iteration's stage writes buf[ti&1], which
        //    this iteration just read. Raw barrier — no vmcnt drain.
        if (ti + 1 < NT) __builtin_amdgcn_s_barrier();
    }

    // Coalesced epilogue: 16 lanes cover t0..t0+15 -> full 64B lines.
    #pragma unroll
    for (int rf = 0; rf < 2; ++rf)
        #pragma unroll
        for (int r = 0; r < 4; ++r) {
            const int brow = wave * 32 + rf * 16 + l4 * 4 + r;
            out[(size_t)brow * T_DIM + t0 + l15] = outv[rf][r];
        }
}

extern "C" void kernel_launch(void* const* d_in, const int* in_sizes, int n_in,
                              void* d_out, int out_size, void* d_ws, size_t ws_size,
                              hipStream_t stream) {
    const float* x  = (const float*)d_in[0];
    const float* W1 = (const float*)d_in[1];
    const float* b1 = (const float*)d_in[2];
    const float* W2 = (const float*)d_in[3];
    const float* b2 = (const float*)d_in[4];
    float* out = (float*)d_out;

    dim3 grid(T_DIM / NT);
    dim3 block(256);
    hipLaunchKernelGGL(fgbn_kernel, grid, block, 0, stream,
                       x, W1, b1, W2, b2, out);
}